// Round 2
// baseline (324.799 us; speedup 1.0000x reference)
//
#include <hip/hip_runtime.h>
#include <hip/hip_fp16.h>

#define B_ 4
#define C_ 64
#define H_ 256
#define W_ 320
#define N_ 9
#define TOT (B_*N_*H_*W_)          // 2949120
#define HW_ (H_*W_)                // 81920
#define HWC (H_*W_*C_)             // 5242880

// ws layout: [0, NHWC_HALFS*2) fp16 NHWC image; then folded params (floats)
#define NHWC_HALFS (B_*H_*W_*C_)   // 20,971,520 halfs = 41,943,040 bytes
#define PRM_OFF_BYTES (NHWC_HALFS*2)
// param floats: [0,128) w0f ; [128,144) b0 ; [144,272) w1f ; [272,280) b1 ; [280,288) simw ; [288] simb

union H2x4U { float4 f; __half2 h[4]; };

__global__ __launch_bounds__(512) void fold_params(
    const float* __restrict__ w0, const float* __restrict__ g0, const float* __restrict__ be0,
    const float* __restrict__ mu0, const float* __restrict__ va0,
    const float* __restrict__ w1, const float* __restrict__ g1, const float* __restrict__ be1,
    const float* __restrict__ mu1, const float* __restrict__ va1,
    const float* __restrict__ sw, const float* __restrict__ sb, float* __restrict__ prm)
{
    int t = threadIdx.x;
    if (t < 128) {
        int o = t >> 3;
        float a = g0[o] / sqrtf(va0[o] + 1e-5f);
        prm[t] = w0[t] * a;
    } else if (t < 144) {
        int o = t - 128;
        float a = g0[o] / sqrtf(va0[o] + 1e-5f);
        prm[128 + o] = be0[o] - mu0[o] * a;
    } else if (t < 272) {
        int i = t - 144;
        int c = i >> 4;
        float a = g1[c] / sqrtf(va1[c] + 1e-5f);
        prm[144 + i] = w1[i] * a;
    } else if (t < 280) {
        int c = t - 272;
        float a = g1[c] / sqrtf(va1[c] + 1e-5f);
        prm[272 + c] = be1[c] - mu1[c] * a;
    } else if (t < 288) {
        prm[t] = sw[t - 280];
    } else if (t == 288) {
        prm[288] = sb[0];
    }
}

// NCHW fp32 -> NHWC fp16 transpose, v2.
// One block = one b x 64-pixel strip x all 64 channels.
// Phase A: channel-pair scalar loads (coalesced 256B/wave), pack half2,
//          conflict-free ds_write_b32 into [pixel][channel] tile (pitch 68 halfs).
// Phase B: read 8 halfs per pixel, store uint4 (16B/lane, 1KB/wave coalesced).
__global__ __launch_bounds__(256) void nchw_to_nhwc_fp16(const float* __restrict__ in,
                                                         __half* __restrict__ out)
{
    __shared__ unsigned int tile[64 * 34];   // pitch 34 words = 68 halfs = 136B (8B aligned rows)
    const int blk = blockIdx.x;
    const int b   = blk / (HW_ / 64);
    const int hw0 = (blk % (HW_ / 64)) * 64;
    const int tid = threadIdx.x;
    const int px  = tid & 63;                // pixel within strip
    const int q   = tid >> 6;                // 0..3

    const float* src = in + (size_t)b * HWC + hw0;
    // Phase A: 8 iters x 2 channels -> 64 channels
#pragma unroll
    for (int i = 0; i < 8; ++i) {
        int c = i * 8 + q * 2;
        float f0 = src[(size_t)c * HW_ + px];
        float f1 = src[(size_t)(c + 1) * HW_ + px];
        __half2 h = __floats2half2_rn(f0, f1);
        tile[px * 34 + (c >> 1)] = *(unsigned int*)&h;
    }
    __syncthreads();

    // Phase B: 2 iters, each thread: pixel p, channels c0..c0+7 (4 words) -> uint4 store
    __half* dstbase = out + ((size_t)b * HW_ + hw0) * C_;
#pragma unroll
    for (int j = 0; j < 2; ++j) {
        int p  = j * 32 + (tid >> 3);
        int cg = tid & 7;                    // channel-group (8 halfs)
        const unsigned int* r = &tile[p * 34 + cg * 4];
        uint4 v;
        v.x = r[0]; v.y = r[1]; v.z = r[2]; v.w = r[3];
        *(uint4*)(dstbase + (size_t)p * C_ + cg * 8) = v;
    }
}

__device__ __forceinline__ __half2 bl_acc(__half2 a00, __half2 a01, __half2 a10, __half2 a11,
                                          __half2 r, __half2 wxh, __half2 wyh, __half2 acc)
{
    __half2 top = __hfma2(wxh, __hsub2(a01, a00), a00);
    __half2 bot = __hfma2(wxh, __hsub2(a11, a10), a10);
    __half2 s   = __hfma2(wyh, __hsub2(bot, top), top);
    return __hfma2(s, r, acc);
}

__global__ __launch_bounds__(256) void fwn_main(const __half* __restrict__ img,   // NHWC fp16
                                                const float* __restrict__ grid,
                                                const float* __restrict__ prm,
                                                float* __restrict__ out)
{
    __shared__ float wlds[256][9];    // [local pixel][group], pad 9 -> ~2-way max
    const int tid  = threadIdx.x;
    const int lane = tid & 63;
    const int wv   = tid >> 6;
    const int g    = lane & 7;        // group
    const int sub  = lane >> 3;       // pixel-in-octet
    const int pix0 = blockIdx.x * 256;
    const int g8   = g * 8;

    // ---------------- phase 1: gather + per-group weighted dot ----------------
#pragma unroll 2
    for (int p8 = 0; p8 < 8; ++p8) {
        int local = wv * 64 + p8 * 8 + sub;
        int P = pix0 + local;

        float2 gxy = ((const float2*)grid)[P];
        float ix = fminf(fmaxf((gxy.x + 1.f) * (W_ * 0.5f) - 0.5f, 0.f), (float)(W_ - 1));
        float iy = fminf(fmaxf((gxy.y + 1.f) * (H_ * 0.5f) - 0.5f, 0.f), (float)(H_ - 1));
        float x0f = floorf(ix), y0f = floorf(iy);
        float wx = ix - x0f, wy = iy - y0f;
        int x0 = (int)x0f, y0 = (int)y0f;
        int x1 = min(x0 + 1, W_ - 1), y1 = min(y0 + 1, H_ - 1);

        unsigned up = (unsigned)P;
        unsigned w_ = up % W_;
        unsigned t1 = up / W_;
        unsigned h_ = t1 & (H_ - 1);
        unsigned b_ = (t1 >> 8) / N_;

        int base = (int)(b_ * HWC) + g8;
        const __half* rp  = img + base + (int)(h_ * W_ + w_) * C_;
        const __half* p00 = img + base + (y0 * W_ + x0) * C_;
        const __half* p01 = img + base + (y0 * W_ + x1) * C_;
        const __half* p10 = img + base + (y1 * W_ + x0) * C_;
        const __half* p11 = img + base + (y1 * W_ + x1) * C_;

        H2x4U r, v00, v01, v10, v11;
        r.f   = *(const float4*)rp;
        v00.f = *(const float4*)p00;
        v01.f = *(const float4*)p01;
        v10.f = *(const float4*)p10;
        v11.f = *(const float4*)p11;

        __half2 wxh = __float2half2_rn(wx);
        __half2 wyh = __float2half2_rn(wy);
        __half2 acc = __float2half2_rn(0.f);
        acc = bl_acc(v00.h[0], v01.h[0], v10.h[0], v11.h[0], r.h[0], wxh, wyh, acc);
        acc = bl_acc(v00.h[1], v01.h[1], v10.h[1], v11.h[1], r.h[1], wxh, wyh, acc);
        acc = bl_acc(v00.h[2], v01.h[2], v10.h[2], v11.h[2], r.h[2], wxh, wyh, acc);
        acc = bl_acc(v00.h[3], v01.h[3], v10.h[3], v11.h[3], r.h[3], wxh, wyh, acc);

        float2 f = __half22float2(acc);
        wlds[local][g] = (f.x + f.y) * 0.125f;
    }

    __syncthreads();

    // ---------------- phase 2: per-pixel MLP ----------------
    float wv8[8];
#pragma unroll
    for (int i = 0; i < 8; ++i) wv8[i] = wlds[tid][i];

    float h0[16];
#pragma unroll
    for (int o = 0; o < 16; ++o) {
        float a = prm[128 + o];
#pragma unroll
        for (int gg = 0; gg < 8; ++gg) a = fmaf(prm[o * 8 + gg], wv8[gg], a);
        h0[o] = fmaxf(a, 0.f);
    }
    float s = prm[288];
#pragma unroll
    for (int c = 0; c < 8; ++c) {
        float a = prm[272 + c];
#pragma unroll
        for (int o = 0; o < 16; ++o) a = fmaf(prm[144 + c * 16 + o], h0[o], a);
        float h1 = fmaxf(a, 0.f);
        s = fmaf(prm[280 + c], h1, s);
    }
    out[pix0 + tid] = 1.f / (1.f + __expf(-s));
}

extern "C" void kernel_launch(void* const* d_in, const int* in_sizes, int n_in,
                              void* d_out, int out_size, void* d_ws, size_t ws_size,
                              hipStream_t stream)
{
    const float* ref   = (const float*)d_in[0];
    const float* grid  = (const float*)d_in[1];
    const float* w0    = (const float*)d_in[2];
    const float* g0    = (const float*)d_in[3];
    const float* be0   = (const float*)d_in[4];
    const float* mu0   = (const float*)d_in[5];
    const float* va0   = (const float*)d_in[6];
    const float* w1    = (const float*)d_in[7];
    const float* g1    = (const float*)d_in[8];
    const float* be1   = (const float*)d_in[9];
    const float* mu1   = (const float*)d_in[10];
    const float* va1   = (const float*)d_in[11];
    const float* sw    = (const float*)d_in[12];
    const float* sb    = (const float*)d_in[13];
    float* out = (float*)d_out;

    __half* img = (__half*)d_ws;
    float* prm  = (float*)((char*)d_ws + PRM_OFF_BYTES);

    fold_params<<<1, 512, 0, stream>>>(w0, g0, be0, mu0, va0, w1, g1, be1, mu1, va1, sw, sb, prm);
    nchw_to_nhwc_fp16<<<B_ * (HW_ / 64), 256, 0, stream>>>(ref, img);
    fwn_main<<<TOT / 256, 256, 0, stream>>>(img, grid, prm, out);
}

// Round 4
// 321.191 us; speedup vs baseline: 1.0112x; 1.0112x over previous
//
#include <hip/hip_runtime.h>
#include <hip/hip_fp16.h>

#define B_ 4
#define C_ 64
#define H_ 256
#define W_ 320
#define N_ 9
#define TOT (B_*N_*H_*W_)          // 2949120
#define HW_ (H_*W_)                // 81920
#define HWC (H_*W_*C_)             // 5242880

// ws layout: [0, NHWC_HALFS*2) fp16 NHWC image; then folded params (floats)
#define NHWC_HALFS (B_*H_*W_*C_)   // 41,943,040 bytes
#define PRM_OFF_BYTES (NHWC_HALFS*2)
// param floats: [0,128) w0f ; [128,144) b0 ; [144,272) w1f ; [272,280) b1 ; [280,288) simw ; [288] simb

union H2x4U { float4 f; __half2 h[4]; };

__global__ __launch_bounds__(512) void fold_params(
    const float* __restrict__ w0, const float* __restrict__ g0, const float* __restrict__ be0,
    const float* __restrict__ mu0, const float* __restrict__ va0,
    const float* __restrict__ w1, const float* __restrict__ g1, const float* __restrict__ be1,
    const float* __restrict__ mu1, const float* __restrict__ va1,
    const float* __restrict__ sw, const float* __restrict__ sb, float* __restrict__ prm)
{
    int t = threadIdx.x;
    if (t < 128) {
        int o = t >> 3;
        float a = g0[o] / sqrtf(va0[o] + 1e-5f);
        prm[t] = w0[t] * a;
    } else if (t < 144) {
        int o = t - 128;
        float a = g0[o] / sqrtf(va0[o] + 1e-5f);
        prm[128 + o] = be0[o] - mu0[o] * a;
    } else if (t < 272) {
        int i = t - 144;
        int c = i >> 4;
        float a = g1[c] / sqrtf(va1[c] + 1e-5f);
        prm[144 + i] = w1[i] * a;
    } else if (t < 280) {
        int c = t - 272;
        float a = g1[c] / sqrtf(va1[c] + 1e-5f);
        prm[272 + c] = be1[c] - mu1[c] * a;
    } else if (t < 288) {
        prm[t] = sw[t - 280];
    } else if (t == 288) {
        prm[288] = sb[0];
    }
}

// NCHW fp32 -> NHWC fp16 transpose (round-2 version, unchanged).
__global__ __launch_bounds__(256) void nchw_to_nhwc_fp16(const float* __restrict__ in,
                                                         __half* __restrict__ out)
{
    __shared__ unsigned int tile[64 * 34];
    const int blk = blockIdx.x;
    const int b   = blk / (HW_ / 64);
    const int hw0 = (blk % (HW_ / 64)) * 64;
    const int tid = threadIdx.x;
    const int px  = tid & 63;
    const int q   = tid >> 6;

    const float* src = in + (size_t)b * HWC + hw0;
#pragma unroll
    for (int i = 0; i < 8; ++i) {
        int c = i * 8 + q * 2;
        float f0 = src[(size_t)c * HW_ + px];
        float f1 = src[(size_t)(c + 1) * HW_ + px];
        __half2 h = __floats2half2_rn(f0, f1);
        tile[px * 34 + (c >> 1)] = *(unsigned int*)&h;
    }
    __syncthreads();

    __half* dstbase = out + ((size_t)b * HW_ + hw0) * C_;
#pragma unroll
    for (int j = 0; j < 2; ++j) {
        int p  = j * 32 + (tid >> 3);
        int cg = tid & 7;
        const unsigned int* r = &tile[p * 34 + cg * 4];
        uint4 v;
        v.x = r[0]; v.y = r[1]; v.z = r[2]; v.w = r[3];
        *(uint4*)(dstbase + (size_t)p * C_ + cg * 8) = v;
    }
}

__device__ __forceinline__ __half2 bl_acc(__half2 a00, __half2 a01, __half2 a10, __half2 a11,
                                          __half2 r, __half2 wxh, __half2 wyh, __half2 acc)
{
    __half2 top = __hfma2(wxh, __hsub2(a01, a00), a00);
    __half2 bot = __hfma2(wxh, __hsub2(a11, a10), a10);
    __half2 s   = __hfma2(wyh, __hsub2(bot, top), top);
    return __hfma2(s, r, acc);
}

__device__ __forceinline__ float gd_compute(const H2x4U& r, const H2x4U& v00, const H2x4U& v01,
                                            const H2x4U& v10, const H2x4U& v11, float wx, float wy)
{
    __half2 wxh = __float2half2_rn(wx);
    __half2 wyh = __float2half2_rn(wy);
    __half2 acc = __float2half2_rn(0.f);
    acc = bl_acc(v00.h[0], v01.h[0], v10.h[0], v11.h[0], r.h[0], wxh, wyh, acc);
    acc = bl_acc(v00.h[1], v01.h[1], v10.h[1], v11.h[1], r.h[1], wxh, wyh, acc);
    acc = bl_acc(v00.h[2], v01.h[2], v10.h[2], v11.h[2], r.h[2], wxh, wyh, acc);
    acc = bl_acc(v00.h[3], v01.h[3], v10.h[3], v11.h[3], r.h[3], wxh, wyh, acc);
    float2 f = __half22float2(acc);
    return (f.x + f.y) * 0.125f;
}

__global__ __launch_bounds__(256) void fwn_main(const __half* __restrict__ img,   // NHWC fp16
                                                const float* __restrict__ grid,
                                                const float* __restrict__ prm,
                                                float* __restrict__ out)
{
    __shared__ float wlds[256][9];    // [local pixel][group]
    __shared__ int   ash[256 * 9];    // per-pixel addr pack: o00,dx,dy,oref,wx,wy (pitch 9 -> conflict-free)
    const int tid  = threadIdx.x;
    const int lane = tid & 63;
    const int wv   = tid >> 6;
    const int g    = lane & 7;
    const int sub  = lane >> 3;
    const int pix0 = blockIdx.x * 256;
    const int g8   = g * 8;

    // ---------------- prepass: per-pixel address math, once ----------------
    {
        int P = pix0 + tid;
        float2 gxy = ((const float2*)grid)[P];
        float ix = fminf(fmaxf((gxy.x + 1.f) * (W_ * 0.5f) - 0.5f, 0.f), (float)(W_ - 1));
        float iy = fminf(fmaxf((gxy.y + 1.f) * (H_ * 0.5f) - 0.5f, 0.f), (float)(H_ - 1));
        float x0f = floorf(ix), y0f = floorf(iy);
        int x0 = (int)x0f, y0 = (int)y0f;
        int dx = (x0 < W_ - 1) ? C_ : 0;
        int dy = (y0 < H_ - 1) ? W_ * C_ : 0;

        unsigned up = (unsigned)P;
        unsigned w_ = up % W_;
        unsigned t1 = up / W_;
        unsigned h_ = t1 & (H_ - 1);
        unsigned b_ = (t1 >> 8) / N_;

        int base = (int)(b_ * HWC);
        int r9 = tid * 9;
        ash[r9 + 0] = base + (y0 * W_ + x0) * C_;
        ash[r9 + 1] = dx;
        ash[r9 + 2] = dy;
        ash[r9 + 3] = base + (int)(h_ * W_ + w_) * C_;
        ash[r9 + 4] = __float_as_int(ix - x0f);
        ash[r9 + 5] = __float_as_int(iy - y0f);
    }
    __syncthreads();

    // ---------------- phase 1: pipelined gathers (2 pixels deep) ----------------
#pragma unroll
    for (int pp = 0; pp < 8; pp += 2) {
        const int rA = (wv * 64 + pp * 8 + sub) * 9;
        const int rB = rA + 8 * 9;

        // --- issue set A loads
        int oA  = ash[rA + 0] + g8;
        int dxA = ash[rA + 1];
        int dyA = ash[rA + 2];
        int orA = ash[rA + 3] + g8;
        float wxA = __int_as_float(ash[rA + 4]);
        float wyA = __int_as_float(ash[rA + 5]);
        H2x4U ra, a00, a01, a10, a11;
        ra.f  = *(const float4*)(img + orA);
        a00.f = *(const float4*)(img + oA);
        a01.f = *(const float4*)(img + oA + dxA);
        a10.f = *(const float4*)(img + oA + dyA);
        a11.f = *(const float4*)(img + oA + dxA + dyA);

        // --- issue set B loads
        int oB  = ash[rB + 0] + g8;
        int dxB = ash[rB + 1];
        int dyB = ash[rB + 2];
        int orB = ash[rB + 3] + g8;
        float wxB = __int_as_float(ash[rB + 4]);
        float wyB = __int_as_float(ash[rB + 5]);
        H2x4U rb, b00, b01, b10, b11;
        rb.f  = *(const float4*)(img + orB);
        b00.f = *(const float4*)(img + oB);
        b01.f = *(const float4*)(img + oB + dxB);
        b10.f = *(const float4*)(img + oB + dyB);
        b11.f = *(const float4*)(img + oB + dxB + dyB);

        // --- consume
        wlds[wv * 64 + pp * 8 + sub][g]     = gd_compute(ra, a00, a01, a10, a11, wxA, wyA);
        wlds[wv * 64 + pp * 8 + sub + 8][g] = gd_compute(rb, b00, b01, b10, b11, wxB, wyB);
    }

    __syncthreads();

    // ---------------- phase 2: per-pixel MLP ----------------
    float wv8[8];
#pragma unroll
    for (int i = 0; i < 8; ++i) wv8[i] = wlds[tid][i];

    float h0[16];
#pragma unroll
    for (int o = 0; o < 16; ++o) {
        float a = prm[128 + o];
#pragma unroll
        for (int gg = 0; gg < 8; ++gg) a = fmaf(prm[o * 8 + gg], wv8[gg], a);
        h0[o] = fmaxf(a, 0.f);
    }
    float s = prm[288];
#pragma unroll
    for (int c = 0; c < 8; ++c) {
        float a = prm[272 + c];
#pragma unroll
        for (int o = 0; o < 16; ++o) a = fmaf(prm[144 + c * 16 + o], h0[o], a);
        float h1 = fmaxf(a, 0.f);
        s = fmaf(prm[280 + c], h1, s);
    }
    out[pix0 + tid] = 1.f / (1.f + __expf(-s));
}

extern "C" void kernel_launch(void* const* d_in, const int* in_sizes, int n_in,
                              void* d_out, int out_size, void* d_ws, size_t ws_size,
                              hipStream_t stream)
{
    const float* ref   = (const float*)d_in[0];
    const float* grd   = (const float*)d_in[1];
    const float* w0    = (const float*)d_in[2];
    const float* g0    = (const float*)d_in[3];
    const float* be0   = (const float*)d_in[4];
    const float* mu0   = (const float*)d_in[5];
    const float* va0   = (const float*)d_in[6];
    const float* w1    = (const float*)d_in[7];
    const float* g1    = (const float*)d_in[8];
    const float* be1   = (const float*)d_in[9];
    const float* mu1   = (const float*)d_in[10];
    const float* va1   = (const float*)d_in[11];
    const float* sw    = (const float*)d_in[12];
    const float* sb    = (const float*)d_in[13];
    float* out = (float*)d_out;

    __half* img = (__half*)d_ws;
    float* prm  = (float*)((char*)d_ws + PRM_OFF_BYTES);

    fold_params<<<1, 512, 0, stream>>>(w0, g0, be0, mu0, va0, w1, g1, be1, mu1, va1, sw, sb, prm);
    nchw_to_nhwc_fp16<<<B_ * (HW_ / 64), 256, 0, stream>>>(ref, img);
    fwn_main<<<TOT / 256, 256, 0, stream>>>(img, grd, prm, out);
}